// Round 1
// baseline (10258.458 us; speedup 1.0000x reference)
//
#include <hip/hip_runtime.h>
#include <math.h>

#define TT 1024      // sequence length
#define EE 1024      // embed dim
#define HH 16        // heads
#define DD 64        // head dim
#define VV 32000
#define F32_EPS 1.1920928955078125e-07f

// ---------- block reduce helpers (blockDim.x == 256 assumed) ----------
__device__ __forceinline__ float bsum(float v) {
    __shared__ float red[256];
    int t = threadIdx.x;
    red[t] = v; __syncthreads();
    #pragma unroll
    for (int s = 128; s > 0; s >>= 1) {
        if (t < s) red[t] += red[t + s];
        __syncthreads();
    }
    float r = red[0]; __syncthreads();
    return r;
}
__device__ __forceinline__ float bmax(float v) {
    __shared__ float red[256];
    int t = threadIdx.x;
    red[t] = v; __syncthreads();
    #pragma unroll
    for (int s = 128; s > 0; s >>= 1) {
        if (t < s) red[t] = fmaxf(red[t], red[t + s]);
        __syncthreads();
    }
    float r = red[0]; __syncthreads();
    return r;
}

// ---------- weight abs-mean: stage 1 partial sums ----------
__global__ __launch_bounds__(256) void wabs_partial(const float* __restrict__ w,
                                                    long long n,
                                                    float* __restrict__ part) {
    float s = 0.f;
    long long stride = (long long)gridDim.x * blockDim.x;
    for (long long i = (long long)blockIdx.x * blockDim.x + threadIdx.x; i < n; i += stride)
        s += fabsf(w[i]);
    s = bsum(s);
    if (threadIdx.x == 0) part[blockIdx.x] = s;
}

// ---------- weight abs-mean: stage 2 (29 slots), writes [ws, clip(mean,1e-5)] ----------
__global__ __launch_bounds__(256) void wscale_final(const float* __restrict__ part,
                                                    float* __restrict__ wsc) {
    int slot = blockIdx.x;
    long long n;
    if (slot < 8)       n = 3072LL * 1024LL;   // wqkv[l,i]
    else if (slot < 16) n = 1024LL * 1024LL;   // wproj[l,i]
    else if (slot < 20) n = 4096LL * 1024LL;   // wfc1[l]
    else if (slot < 24) n = 4096LL * 4096LL;   // wfc2[l]
    else if (slot < 28) n = 1024LL * 4096LL;   // wfcp[l]
    else                n = 32000LL * 1024LL;  // wte
    __shared__ double red[256];
    int t = threadIdx.x;
    double s = 0.0;
    for (int i = t; i < 1024; i += 256) s += (double)part[slot * 1024 + i];
    red[t] = s; __syncthreads();
    for (int st = 128; st > 0; st >>= 1) {
        if (t < st) red[t] += red[t + st];
        __syncthreads();
    }
    if (t == 0) {
        float mean = (float)(red[0] / (double)n);
        float mc = fmaxf(mean, 1e-5f);
        wsc[slot * 2 + 0] = 1.0f / mc;  // ws (quant multiplier)
        wsc[slot * 2 + 1] = mc;         // dequant multiplier
    }
}

// ---------- embedding: x[t] = wte[idx[t]] + wpe[t] ----------
__global__ __launch_bounds__(256) void embed_k(const int* __restrict__ idx,
                                               const float* __restrict__ wte,
                                               const float* __restrict__ wpe,
                                               float* __restrict__ x) {
    int t = blockIdx.x;
    size_t row = (size_t)idx[t] * EE;
    for (int e = threadIdx.x; e < EE; e += 256)
        x[(size_t)t * EE + e] = wte[row + e] + wpe[(size_t)t * EE + e];
}

// ---------- plain rms over rows of width Wd ----------
__global__ __launch_bounds__(256) void rms_k(const float* __restrict__ X,
                                             float* __restrict__ Y, int Wd) {
    size_t base = (size_t)blockIdx.x * Wd;
    float ss = 0.f;
    for (int i = threadIdx.x; i < Wd; i += 256) { float v = X[base + i]; ss += v * v; }
    ss = bsum(ss);
    float r = 1.0f / sqrtf(ss / (float)Wd + F32_EPS);
    for (int i = threadIdx.x; i < Wd; i += 256) Y[base + i] = X[base + i] * r;
}

// ---------- rms + activation quantize (store dequantized f32) ----------
__global__ __launch_bounds__(256) void rmsq_k(const float* __restrict__ X,
                                              float* __restrict__ Y, int Wd) {
    __shared__ float buf[4096];
    size_t base = (size_t)blockIdx.x * Wd;
    float ss = 0.f;
    for (int i = threadIdx.x; i < Wd; i += 256) { float v = X[base + i]; buf[i] = v; ss += v * v; }
    ss = bsum(ss);
    float r = 1.0f / sqrtf(ss / (float)Wd + F32_EPS);
    float mx = 0.f;
    for (int i = threadIdx.x; i < Wd; i += 256) {
        float rn = buf[i] * r; buf[i] = rn; mx = fmaxf(mx, fabsf(rn));
    }
    mx = bmax(mx);
    float s = 127.0f / fmaxf(mx, 1e-5f);
    for (int i = threadIdx.x; i < Wd; i += 256) {
        float q = rintf(buf[i] * s);              // round half-to-even, like jnp.round
        q = fminf(fmaxf(q, -128.f), 127.f);
        Y[base + i] = q / s;
    }
}

// ---------- C[M,N] = epi( A[M,K] @ dequant(W[N,K])^T ) ; mode 1 = relu^2 ----------
__global__ __launch_bounds__(256) void mm_bitw(const float* __restrict__ A,
                                               const float* __restrict__ W,
                                               const float* __restrict__ wsc,
                                               float* __restrict__ C,
                                               int M, int N, int K, int mode) {
    __shared__ float As[64][17];
    __shared__ float Bs[64][17];
    int tid = threadIdx.x;
    int tx = tid & 15, ty = tid >> 4;
    int m0 = blockIdx.y * 64, n0 = blockIdx.x * 64;
    float ws = wsc[0], mc = wsc[1];
    float c[4][4] = {};
    int lr = tid >> 2, lc = (tid & 3) * 4;
    for (int k0 = 0; k0 < K; k0 += 16) {
        float4 a4 = *reinterpret_cast<const float4*>(A + (size_t)(m0 + lr) * K + k0 + lc);
        As[lr][lc + 0] = a4.x; As[lr][lc + 1] = a4.y; As[lr][lc + 2] = a4.z; As[lr][lc + 3] = a4.w;
        float4 w4 = *reinterpret_cast<const float4*>(W + (size_t)(n0 + lr) * K + k0 + lc);
        Bs[lr][lc + 0] = fminf(fmaxf(rintf(w4.x * ws), -1.f), 1.f) * mc;
        Bs[lr][lc + 1] = fminf(fmaxf(rintf(w4.y * ws), -1.f), 1.f) * mc;
        Bs[lr][lc + 2] = fminf(fmaxf(rintf(w4.z * ws), -1.f), 1.f) * mc;
        Bs[lr][lc + 3] = fminf(fmaxf(rintf(w4.w * ws), -1.f), 1.f) * mc;
        __syncthreads();
        #pragma unroll
        for (int kk = 0; kk < 16; kk++) {
            float a[4], b[4];
            #pragma unroll
            for (int i = 0; i < 4; i++) a[i] = As[ty * 4 + i][kk];
            #pragma unroll
            for (int j = 0; j < 4; j++) b[j] = Bs[tx * 4 + j][kk];
            #pragma unroll
            for (int i = 0; i < 4; i++)
                #pragma unroll
                for (int j = 0; j < 4; j++)
                    c[i][j] = fmaf(a[i], b[j], c[i][j]);
        }
        __syncthreads();
    }
    #pragma unroll
    for (int i = 0; i < 4; i++) {
        #pragma unroll
        for (int j = 0; j < 4; j++) {
            float v = c[i][j];
            if (mode == 1) { v = fmaxf(v, 0.f); v = v * v; }
            C[(size_t)(m0 + ty * 4 + i) * N + n0 + tx * 4 + j] = v;
        }
    }
}

// ---------- per-(h,t) head rms + rotary (theta = h * freq[d], faithful quirk) ----------
__device__ __forceinline__ float rms64(float v) {
    float ss = v * v;
    #pragma unroll
    for (int m = 32; m >= 1; m >>= 1) ss += __shfl_xor(ss, m);
    return v * (1.0f / sqrtf(ss * (1.0f / 64.0f) + F32_EPS));
}

__global__ __launch_bounds__(64) void headprep_k(const float* __restrict__ qkv,
                                                 float* __restrict__ qh,
                                                 float* __restrict__ kh,
                                                 float* __restrict__ vh) {
    int t = blockIdx.x, h = blockIdx.y, d = threadIdx.x;
    size_t ib = (size_t)t * (3 * EE) + (size_t)h * DD + d;
    float q = rms64(qkv[ib]);
    float k = rms64(qkv[ib + EE]);
    float v = rms64(qkv[ib + 2 * EE]);
    int dd = d & 31;
    float fr = (dd < 16) ? exp2f((float)dd * (-10.0f / 15.0f)) : 0.0f; // (1/1024)^(dd/15)
    float th = (float)h * fr;
    float cs = cosf(th), sn = sinf(th);
    float pq = __shfl_xor(q, 32), pk = __shfl_xor(k, 32);
    float sg = (d < 32) ? 1.0f : -1.0f;
    float qo = q * cs + sg * pq * sn;
    float ko = k * cs + sg * pk * sn;
    size_t ob = ((size_t)h * TT + t) * DD + d;
    qh[ob] = qo; kh[ob] = ko; vh[ob] = v;
}

// ---------- scores[h,i,j] = 0.12 * q_h[i] . k_h[j]  (lower-triangular tiles only) ----------
__global__ __launch_bounds__(256) void scores_k(const float* __restrict__ qh,
                                                const float* __restrict__ kh,
                                                float* __restrict__ sc) {
    int jt = blockIdx.x, it = blockIdx.y, h = blockIdx.z;
    if (jt > it) return;
    __shared__ float Q[64][65], Kt[64][65];
    int tid = threadIdx.x, tx = tid & 15, ty = tid >> 4;
    for (int p = 0; p < 4; p++) {
        int idx = p * 256 + tid;
        int r = idx >> 4, cc = (idx & 15) * 4;
        float4 q4 = *reinterpret_cast<const float4*>(qh + ((size_t)h * TT + it * 64 + r) * DD + cc);
        Q[r][cc] = q4.x; Q[r][cc + 1] = q4.y; Q[r][cc + 2] = q4.z; Q[r][cc + 3] = q4.w;
        float4 k4 = *reinterpret_cast<const float4*>(kh + ((size_t)h * TT + jt * 64 + r) * DD + cc);
        Kt[r][cc] = k4.x; Kt[r][cc + 1] = k4.y; Kt[r][cc + 2] = k4.z; Kt[r][cc + 3] = k4.w;
    }
    __syncthreads();
    float c[4][4] = {};
    for (int d = 0; d < 64; d++) {
        float a[4], b[4];
        #pragma unroll
        for (int i = 0; i < 4; i++) a[i] = Q[ty * 4 + i][d];
        #pragma unroll
        for (int j = 0; j < 4; j++) b[j] = Kt[tx * 4 + j][d];
        #pragma unroll
        for (int i = 0; i < 4; i++)
            #pragma unroll
            for (int j = 0; j < 4; j++)
                c[i][j] = fmaf(a[i], b[j], c[i][j]);
    }
    #pragma unroll
    for (int i = 0; i < 4; i++)
        #pragma unroll
        for (int j = 0; j < 4; j++)
            sc[((size_t)h * TT + it * 64 + ty * 4 + i) * TT + jt * 64 + tx * 4 + j] = 0.12f * c[i][j];
}

// ---------- causal softmax per row; zero-fills j>i so PV can read full rows ----------
__global__ __launch_bounds__(256) void softmax_k(float* __restrict__ sc) {
    int i = blockIdx.x, h = blockIdx.y;
    float* row = sc + ((size_t)h * TT + i) * TT;
    int n = i + 1;
    float m = -INFINITY;
    for (int j = threadIdx.x; j < n; j += 256) m = fmaxf(m, row[j]);
    m = bmax(m);
    float s = 0.f;
    for (int j = threadIdx.x; j < n; j += 256) { float e = expf(row[j] - m); row[j] = e; s += e; }
    s = bsum(s);
    for (int j = threadIdx.x; j < TT; j += 256) row[j] = (j < n) ? row[j] / s : 0.0f;
}

// ---------- y[t, h*64+d] = sum_j P[h,t,j] * v_h[j,d] ----------
__global__ __launch_bounds__(256) void pv_k(const float* __restrict__ sc,
                                            const float* __restrict__ vh,
                                            float* __restrict__ y) {
    int it = blockIdx.x, h = blockIdx.y;
    __shared__ float P[64][17];
    __shared__ float Vs[16][64];
    int tid = threadIdx.x, tx = tid & 15, ty = tid >> 4;
    float c[4][4] = {};
    int nk = (it + 1) * 4;           // 16-wide K chunks up to causal bound
    int pr = tid >> 2, pc = (tid & 3) * 4;
    int vr = tid >> 4, vc = (tid & 15) * 4;
    for (int kt = 0; kt < nk; kt++) {
        int j0 = kt * 16;
        float4 p4 = *reinterpret_cast<const float4*>(sc + ((size_t)h * TT + it * 64 + pr) * TT + j0 + pc);
        P[pr][pc] = p4.x; P[pr][pc + 1] = p4.y; P[pr][pc + 2] = p4.z; P[pr][pc + 3] = p4.w;
        float4 v4 = *reinterpret_cast<const float4*>(vh + ((size_t)h * TT + j0 + vr) * DD + vc);
        Vs[vr][vc] = v4.x; Vs[vr][vc + 1] = v4.y; Vs[vr][vc + 2] = v4.z; Vs[vr][vc + 3] = v4.w;
        __syncthreads();
        #pragma unroll
        for (int kk = 0; kk < 16; kk++) {
            float a[4], b[4];
            #pragma unroll
            for (int i = 0; i < 4; i++) a[i] = P[ty * 4 + i][kk];
            #pragma unroll
            for (int j = 0; j < 4; j++) b[j] = Vs[kk][tx * 4 + j];
            #pragma unroll
            for (int i = 0; i < 4; i++)
                #pragma unroll
                for (int j = 0; j < 4; j++)
                    c[i][j] = fmaf(a[i], b[j], c[i][j]);
        }
        __syncthreads();
    }
    #pragma unroll
    for (int i = 0; i < 4; i++)
        #pragma unroll
        for (int j = 0; j < 4; j++)
            y[(size_t)(it * 64 + ty * 4 + i) * EE + h * DD + tx * 4 + j] = c[i][j];
}

// ---------- residual add ----------
__global__ __launch_bounds__(256) void add_k(float* __restrict__ x, const float* __restrict__ b) {
    int i = blockIdx.x * 256 + threadIdx.x;
    x[i] += b[i];
}

// ---------- loss: per-row (logsumexp - logit[target]) ----------
__global__ __launch_bounds__(256) void lossrow_k(const float* __restrict__ logits,
                                                 const int* __restrict__ tgt,
                                                 float* __restrict__ rrow) {
    int t = blockIdx.x;
    const float* row = logits + (size_t)t * VV;
    float m = -INFINITY;
    for (int j = threadIdx.x; j < VV; j += 256) m = fmaxf(m, row[j]);
    m = bmax(m);
    float s = 0.f;
    for (int j = threadIdx.x; j < VV; j += 256) s += expf(row[j] - m);
    s = bsum(s);
    if (threadIdx.x == 0) rrow[t] = (m + logf(s)) - row[tgt[t]];
}

__global__ __launch_bounds__(256) void lossfin_k(const float* __restrict__ rrow,
                                                 float* __restrict__ out) {
    float s = 0.f;
    for (int i = threadIdx.x; i < TT; i += 256) s += rrow[i];
    s = bsum(s);
    if (threadIdx.x == 0) out[0] = s / 1024.0f;
}

extern "C" void kernel_launch(void* const* d_in, const int* in_sizes, int n_in,
                              void* d_out, int out_size, void* d_ws, size_t ws_size,
                              hipStream_t stream) {
    (void)in_sizes; (void)n_in; (void)out_size; (void)ws_size;
    const int*   idx   = (const int*)d_in[0];
    const int*   tgt   = (const int*)d_in[1];
    const float* wte   = (const float*)d_in[2];
    const float* wpe   = (const float*)d_in[3];
    const float* wqkv  = (const float*)d_in[4];
    const float* wproj = (const float*)d_in[5];
    const float* wfc1  = (const float*)d_in[6];
    const float* wfc2  = (const float*)d_in[7];
    const float* wfcp  = (const float*)d_in[8];
    float* out = (float*)d_out;

    // workspace layout (floats), total ~136 MiB
    float* P = (float*)d_ws;
    float* part = P;  P += 29 * 1024;
    float* wsc  = P;  P += 64;
    float* rrow = P;  P += 1024;
    float* x    = P;  P += 1048576;   // residual [T,E]
    float* xn   = P;  P += 1048576;   // rms(x)
    float* Aq   = P;  P += 4194304;   // quantized activations (max width 4096)
    float* hbuf = P;  P += 4194304;   // ffn hidden
    float* qkvb = P;  P += 3145728;   // [T, 3E]
    float* qh   = P;  P += 1048576;   // [H,T,D]
    float* kh   = P;  P += 1048576;
    float* vh   = P;  P += 1048576;
    float* yb   = P;  P += 1048576;   // attn merge [T,E]
    float* bout = P;  P += 1048576;   // branch output
    float* sc   = P;  P += 16777216;  // scores/probs [H,T,T]

    // ---- weight scales (29 matrices), deterministic two-stage reduction ----
    for (int l = 0; l < 4; l++)
        for (int i = 0; i < 2; i++)
            wabs_partial<<<1024, 256, 0, stream>>>(wqkv + (size_t)(l * 2 + i) * 3072 * 1024,
                                                   3072LL * 1024, part + (l * 2 + i) * 1024);
    for (int l = 0; l < 4; l++)
        for (int i = 0; i < 2; i++)
            wabs_partial<<<1024, 256, 0, stream>>>(wproj + (size_t)(l * 2 + i) * 1024 * 1024,
                                                   1024LL * 1024, part + (8 + l * 2 + i) * 1024);
    for (int l = 0; l < 4; l++)
        wabs_partial<<<1024, 256, 0, stream>>>(wfc1 + (size_t)l * 4096 * 1024,
                                               4096LL * 1024, part + (16 + l) * 1024);
    for (int l = 0; l < 4; l++)
        wabs_partial<<<1024, 256, 0, stream>>>(wfc2 + (size_t)l * 4096 * 4096,
                                               4096LL * 4096, part + (20 + l) * 1024);
    for (int l = 0; l < 4; l++)
        wabs_partial<<<1024, 256, 0, stream>>>(wfcp + (size_t)l * 1024 * 4096,
                                               1024LL * 4096, part + (24 + l) * 1024);
    wabs_partial<<<1024, 256, 0, stream>>>(wte, 32000LL * 1024, part + 28 * 1024);
    wscale_final<<<29, 256, 0, stream>>>(part, wsc);

    embed_k<<<1024, 256, 0, stream>>>(idx, wte, wpe, x);

    for (int l = 0; l < 4; l++) {
        rms_k<<<1024, 256, 0, stream>>>(x, xn, 1024);
        // ---- FFN branch ----
        rmsq_k<<<1024, 256, 0, stream>>>(xn, Aq, 1024);
        mm_bitw<<<dim3(64, 16), 256, 0, stream>>>(Aq, wfc1 + (size_t)l * 4096 * 1024,
                                                  wsc + 2 * (16 + l), hbuf, 1024, 4096, 1024, 1);
        rmsq_k<<<1024, 256, 0, stream>>>(hbuf, Aq, 4096);
        mm_bitw<<<dim3(64, 16), 256, 0, stream>>>(Aq, wfc2 + (size_t)l * 4096 * 4096,
                                                  wsc + 2 * (20 + l), hbuf, 1024, 4096, 4096, 1);
        rmsq_k<<<1024, 256, 0, stream>>>(hbuf, Aq, 4096);
        mm_bitw<<<dim3(16, 16), 256, 0, stream>>>(Aq, wfcp + (size_t)l * 1024 * 4096,
                                                  wsc + 2 * (24 + l), bout, 1024, 1024, 4096, 0);
        add_k<<<4096, 256, 0, stream>>>(x, bout);
        // ---- two attention branches (both read xn) ----
        for (int i = 0; i < 2; i++) {
            rmsq_k<<<1024, 256, 0, stream>>>(xn, Aq, 1024);
            mm_bitw<<<dim3(48, 16), 256, 0, stream>>>(Aq, wqkv + (size_t)(l * 2 + i) * 3072 * 1024,
                                                      wsc + 2 * (l * 2 + i), qkvb, 1024, 3072, 1024, 0);
            headprep_k<<<dim3(1024, 16), 64, 0, stream>>>(qkvb, qh, kh, vh);
            scores_k<<<dim3(16, 16, 16), 256, 0, stream>>>(qh, kh, sc);
            softmax_k<<<dim3(1024, 16), 256, 0, stream>>>(sc);
            pv_k<<<dim3(16, 16), 256, 0, stream>>>(sc, vh, yb);
            rmsq_k<<<1024, 256, 0, stream>>>(yb, Aq, 1024);
            mm_bitw<<<dim3(16, 16), 256, 0, stream>>>(Aq, wproj + (size_t)(l * 2 + i) * 1024 * 1024,
                                                      wsc + 2 * (8 + l * 2 + i), bout, 1024, 1024, 1024, 0);
            add_k<<<4096, 256, 0, stream>>>(x, bout);
        }
    }

    // ---- final norm + lm_head (tied wte) + loss ----
    rms_k<<<1024, 256, 0, stream>>>(x, xn, 1024);
    rmsq_k<<<1024, 256, 0, stream>>>(xn, Aq, 1024);
    mm_bitw<<<dim3(500, 16), 256, 0, stream>>>(Aq, wte, wsc + 2 * 28, out, 1024, 32000, 1024, 0);
    lossrow_k<<<1024, 256, 0, stream>>>(out, tgt, rrow);
    lossfin_k<<<1, 256, 0, stream>>>(rrow, out + (size_t)1024 * 32000);
}